// Round 1
// baseline (652.598 us; speedup 1.0000x reference)
//
#include <hip/hip_runtime.h>
#include <stdint.h>

#define NB   2
#define NN   6
#define NIMG 12
#define CIN  512
#define CMID 512
#define DD   112
#define COUT 80
#define FHh  16
#define FWw  44
#define NPIX 704
#define NPOS 8448
#define KK   4608       // 512*9
#define NXg  128
#define NYg  128
#define YX   16384
#define MAT_STRIDE 56   // doubles per image slot

typedef short short8 __attribute__((ext_vector_type(8)));
typedef float f32x4  __attribute__((ext_vector_type(4)));

__device__ __forceinline__ unsigned short f2bf(float f){
  unsigned u = __float_as_uint(f);
  u += 0x7fffu + ((u >> 16) & 1u);    // RNE
  return (unsigned short)(u >> 16);
}

__device__ __forceinline__ f32x4 mfma16(short8 a, short8 b, f32x4 c){
  return __builtin_amdgcn_mfma_f32_16x16x32_bf16(a, b, c, 0, 0, 0);
}

// ---------------- prep kernels ----------------
__global__ void k_f32_to_bf16(const float* __restrict__ src, unsigned short* __restrict__ dst, int n){
  for (int i = blockIdx.x*blockDim.x + threadIdx.x; i < n; i += gridDim.x*blockDim.x)
    dst[i] = f2bf(src[i]);
}

__global__ void k_bn_prep(const float* __restrict__ g, const float* __restrict__ b,
                          const float* __restrict__ m, const float* __restrict__ v,
                          float* __restrict__ scale, float* __restrict__ bias){
  int t = blockIdx.x*blockDim.x + threadIdx.x;
  if (t < CMID){
    float s = g[t] / sqrtf(v[t] + 1e-5f);
    scale[t] = s;
    bias[t]  = b[t] - m[t]*s;
  }
}

__device__ void inv4(const double* A, double* out){
  double M[4][8];
  for (int i=0;i<4;i++){ for(int j=0;j<4;j++){ M[i][j]=A[i*4+j]; M[i][4+j]=(i==j)?1.0:0.0; } }
  for (int c=0;c<4;c++){
    int piv=c; double best=fabs(M[c][c]);
    for (int r=c+1;r<4;r++){ double a=fabs(M[r][c]); if(a>best){best=a;piv=r;} }
    if (piv!=c){ for(int j=0;j<8;j++){ double tt=M[c][j]; M[c][j]=M[piv][j]; M[piv][j]=tt; } }
    double inv = 1.0 / M[c][c];
    for (int j=0;j<8;j++) M[c][j]*=inv;
    for (int r=0;r<4;r++){ if(r==c) continue; double f=M[r][c];
      for (int j=0;j<8;j++) M[r][j]-=f*M[c][j]; }
  }
  for (int i=0;i<4;i++) for(int j=0;j<4;j++) out[i*4+j]=M[i][4+j];
}
__device__ void mm4(const double* A, const double* Bm, double* C){
  for (int i=0;i<4;i++) for(int j=0;j<4;j++){
    double s=0.0; for(int k=0;k<4;k++) s+=A[i*4+k]*Bm[k*4+j]; C[i*4+j]=s; }
}

__global__ void k_prep_mats(const float* __restrict__ s2e, const float* __restrict__ s2v,
                            const float* __restrict__ intr, const float* __restrict__ ida,
                            const float* __restrict__ refh, const float* __restrict__ bda,
                            double* __restrict__ mats){
  int t = threadIdx.x;
  if (t >= NIMG) return;
  int b = t / NN;
  double Mida[16], Ms2v[16], Mintr[16], Ms2e[16], Mbda[16];
  for (int i=0;i<16;i++){
    Mida[i] =(double)ida [t*16+i];
    Ms2v[i] =(double)s2v [t*16+i];
    Mintr[i]=(double)intr[t*16+i];
    Ms2e[i] =(double)s2e [t*16+i];
    Mbda[i] =(double)bda [b*16+i];
  }
  double* o = mats + (size_t)t*MAT_STRIDE;
  double tmp[16], tmp2[16];
  inv4(Mida, o);                          // iida
  inv4(Mintr, tmp);  mm4(Ms2v, tmp, o+16);          // cv = s2v @ inv(intrin)
  inv4(Ms2v, tmp);   mm4(Ms2e, tmp, tmp2);          // ce = s2e @ inv(s2v)
  mm4(Mbda, tmp2, o+32);                             // fin = bda @ ce
  o[48] = (double)refh[t];
}

// ---------------- geometry ----------------
__global__ void k_geom(const double* __restrict__ mats, int* __restrict__ sid){
  int g = blockIdx.x*blockDim.x + threadIdx.x;       // 946176 exactly
  int img = g / (DD*NPIX); int rem = g - img*(DD*NPIX);
  int d = rem / NPIX; int p = rem - d*NPIX;
  int h = p / FWw; int w = p - h*FWw;
  const double* M = mats + (size_t)img*MAT_STRIDE;
  // frustum coords, replicating fp32 linspace
  float xf = (float)w * (703.0f/43.0f);
  float yf = (float)h * 17.0f;
  float df = 2.0f + (float)d * (56.0f/111.0f);
  double x = (double)xf, y = (double)yf, dep = (double)df;
  double p0 = M[0]*x + M[1]*y + M[2]*dep + M[3];
  double p1 = M[4]*x + M[5]*y + M[6]*dep + M[7];
  double p2 = M[8]*x + M[9]*y + M[10]*dep + M[11];
  double p3 = M[12]*x + M[13]*y + M[14]*dep + M[15];
  double height = M[48] - p2;
  double c0 = p0*10.0, c1 = p1*10.0, c2 = 10.0, c3 = p3;
  const double* C = M + 16;
  double q0 = C[0]*c0 + C[1]*c1 + C[2]*c2 + C[3]*c3;
  double q1 = C[4]*c0 + C[5]*c1 + C[6]*c2 + C[7]*c3;
  double q2 = C[8]*c0 + C[9]*c1 + C[10]*c2 + C[11]*c3;
  double ratio = height / q1;
  double r0 = q0*ratio, r1 = q1*ratio, r2 = q2*ratio, r3 = 1.0;
  const double* F = M + 32;
  double gx = F[0]*r0 + F[1]*r1 + F[2]*r2 + F[3]*r3;
  double gy = F[4]*r0 + F[5]*r1 + F[6]*r2 + F[7]*r3;
  double gz = F[8]*r0 + F[9]*r1 + F[10]*r2 + F[11]*r3;
  float gxf = (float)gx, gyf = (float)gy, gzf = (float)gz;
  const float vcx = (float)(-51.2 + 0.4);
  const float ox = vcx - 0.4f;            // vcoord - vsize/2 in fp32, like reference
  const float oy = ox;
  const float oz = -1.0f - 4.0f;
  float tx = (gxf - ox) / 0.8f;
  float ty = (gyf - oy) / 0.8f;
  float tz = (gzf - oz) / 8.0f;
  int ix = (int)tx, iy = (int)ty, iz = (int)tz;   // trunc-toward-zero like astype(int32)
  bool valid = (tx==tx) && (ty==ty) && (tz==tz) &&
               (ix >= 0) && (ix < NXg) && (iy >= 0) && (iy < NYg) && (iz == 0);
  int b = img / NN;
  sid[g] = valid ? (b*YX + iy*NXg + ix) : -1;
}

// ---------------- im2col ----------------
// Bt layout: [pos_local][k], k = ic*9 + dy*3 + dx  (matches OIHW weight flatten)
template<int SRC_F32>
__global__ void k_im2col(const void* __restrict__ srcv, unsigned short* __restrict__ Bt, int pos0){
  int pos = pos0 + blockIdx.x;
  int img = pos / NPIX; int p = pos - img*NPIX;
  int y = p / FWw; int x = p - y*FWw;
  const float*          sf = (const float*)srcv          + (size_t)img*CIN*NPIX;
  const unsigned short* sh = (const unsigned short*)srcv + (size_t)img*CIN*NPIX;
  unsigned* out = (unsigned*)(Bt + (size_t)blockIdx.x * KK);
  for (int j = threadIdx.x; j < KK/2; j += blockDim.x){
    unsigned short rv[2];
    #pragma unroll
    for (int u = 0; u < 2; ++u){
      int kk = 2*j + u;
      int ic = kk / 9; int r = kk - ic*9;
      int yy = y + r/3 - 1;
      int xx = x + (r - (r/3)*3) - 1;
      unsigned short val = 0;
      if (yy >= 0 && yy < FHh && xx >= 0 && xx < FWw){
        int off = ic*NPIX + yy*FWw + xx;
        val = SRC_F32 ? f2bf(sf[off]) : sh[off];
      }
      rv[u] = val;
    }
    out[j] = (unsigned)rv[0] | ((unsigned)rv[1] << 16);
  }
}

// ---------------- GEMM 128x128, BK=32, bf16 MFMA ----------------
// MODE 0 (conv1): D rows = oc -> write h1[img][oc][p], BN+ReLU, bf16
// MODE 1 (conv2): operands swapped, D rows = pos -> write h2[pos][oc], BN+ReLU, bf16
template<int MODE>
__global__ __launch_bounds__(256) void k_gemm128(const unsigned short* __restrict__ A,
    const unsigned short* __restrict__ Bt, int K,
    const float* __restrict__ scale, const float* __restrict__ bias,
    unsigned short* __restrict__ out, int n0g){
  __shared__ __align__(16) short As[128][32];
  __shared__ __align__(16) short Bs[128][32];
  int t = threadIdx.x;
  int m0 = blockIdx.x * 128;
  int lane = t & 63; int wv = t >> 6; int wm = wv >> 1, wn = wv & 1;
  int q = lane >> 4, ml = lane & 15;
  f32x4 acc[4][4];
  #pragma unroll
  for (int i=0;i<4;i++)
    #pragma unroll
    for (int j=0;j<4;j++) acc[i][j] = (f32x4)0.0f;

  int arow = t >> 1, acol = (t & 1) * 16;
  const unsigned short* pa = A  + (size_t)(m0 + arow)*K + acol;
  const unsigned short* pb = Bt + (size_t)(blockIdx.y*128 + arow)*K + acol;

  for (int kb = 0; kb < K; kb += 32){
    uint4 a0 = *(const uint4*)(pa + kb);
    uint4 a1 = *(const uint4*)(pa + kb + 8);
    uint4 b0 = *(const uint4*)(pb + kb);
    uint4 b1 = *(const uint4*)(pb + kb + 8);
    __syncthreads();
    *(uint4*)&As[arow][acol]   = a0; *(uint4*)&As[arow][acol+8] = a1;
    *(uint4*)&Bs[arow][acol]   = b0; *(uint4*)&Bs[arow][acol+8] = b1;
    __syncthreads();
    short8 fa[4], fb[4];
    #pragma unroll
    for (int mi=0;mi<4;mi++) fa[mi] = *(const short8*)&As[wm*64 + mi*16 + ml][q*8];
    #pragma unroll
    for (int ni=0;ni<4;ni++) fb[ni] = *(const short8*)&Bs[wn*64 + ni*16 + ml][q*8];
    #pragma unroll
    for (int mi=0;mi<4;mi++)
      #pragma unroll
      for (int ni=0;ni<4;ni++){
        if (MODE == 0) acc[mi][ni] = mfma16(fa[mi], fb[ni], acc[mi][ni]);
        else           acc[mi][ni] = mfma16(fb[ni], fa[mi], acc[mi][ni]);
      }
  }

  if (MODE == 0){
    #pragma unroll
    for (int mi=0;mi<4;mi++){
      #pragma unroll
      for (int ni=0;ni<4;ni++){
        int pos = n0g + blockIdx.y*128 + wn*64 + ni*16 + ml;
        int img = pos / NPIX; int p = pos - img*NPIX;
        unsigned short* op = out + (size_t)img*CMID*NPIX + p;
        f32x4 v = acc[mi][ni];
        #pragma unroll
        for (int r=0;r<4;r++){
          int m = m0 + wm*64 + mi*16 + q*4 + r;
          float val = fmaxf(v[r]*scale[m] + bias[m], 0.0f);
          op[(size_t)m*NPIX] = f2bf(val);
        }
      }
    }
  } else {
    #pragma unroll
    for (int mi=0;mi<4;mi++){
      int oc = m0 + wm*64 + mi*16 + ml;
      float s = scale[oc], bb = bias[oc];
      #pragma unroll
      for (int ni=0;ni<4;ni++){
        f32x4 v = acc[mi][ni];
        #pragma unroll
        for (int r=0;r<4;r++){
          int pos = n0g + blockIdx.y*128 + wn*64 + ni*16 + q*4 + r;
          float val = fmaxf(v[r]*s + bb, 0.0f);
          out[(size_t)pos*CMID + oc] = f2bf(val);
        }
      }
    }
  }
}

// ---------------- GEMM for 1x1 conv-out: M=192(BM=64), N=8448, K=512; swapped (pos-major out) ----------------
__global__ __launch_bounds__(256) void k_gemm64(const unsigned short* __restrict__ A,
    const unsigned short* __restrict__ Bt, const float* __restrict__ bout,
    float* __restrict__ hf){
  const int K = 512;
  __shared__ __align__(16) short As[64][32];
  __shared__ __align__(16) short Bs[128][32];
  int t = threadIdx.x;
  int m0 = blockIdx.x*64; int n0 = blockIdx.y*128;
  int lane = t & 63; int wv = t >> 6; int q = lane >> 4, ml = lane & 15;
  f32x4 acc[8];
  #pragma unroll
  for (int i=0;i<8;i++) acc[i] = (f32x4)0.0f;
  int ar = t >> 2, ac = (t & 3) * 8;
  int br = t >> 1, bc = (t & 1) * 16;
  const unsigned short* pa = A  + (size_t)(m0 + ar)*K + ac;
  const unsigned short* pb = Bt + (size_t)(n0 + br)*K + bc;
  for (int kb = 0; kb < K; kb += 32){
    uint4 av = *(const uint4*)(pa + kb);
    uint4 b0 = *(const uint4*)(pb + kb);
    uint4 b1 = *(const uint4*)(pb + kb + 8);
    __syncthreads();
    *(uint4*)&As[ar][ac] = av;
    *(uint4*)&Bs[br][bc] = b0; *(uint4*)&Bs[br][bc+8] = b1;
    __syncthreads();
    short8 fa = *(const short8*)&As[wv*16 + ml][q*8];
    #pragma unroll
    for (int ni=0;ni<8;ni++){
      short8 fb = *(const short8*)&Bs[ni*16 + ml][q*8];
      acc[ni] = mfma16(fb, fa, acc[ni]);     // rows = pos, cols = oc
    }
  }
  int oc = m0 + wv*16 + ml;
  float bb = bout[oc];
  #pragma unroll
  for (int ni=0;ni<8;ni++)
    #pragma unroll
    for (int r=0;r<4;r++){
      int pos = n0 + ni*16 + q*4 + r;
      hf[(size_t)pos*192 + oc] = acc[ni][r] + bb;
    }
}

// ---------------- depth softmax: one wave per position ----------------
__global__ void k_softmax(const float* __restrict__ hf, float* __restrict__ depth){
  int pos = blockIdx.x*4 + (threadIdx.x >> 6);
  int lane = threadIdx.x & 63;
  const float* row = hf + (size_t)pos*192;
  float v0 = row[lane];
  float v1 = (lane < DD-64) ? row[64 + lane] : -1e30f;
  float mx = fmaxf(v0, v1);
  #pragma unroll
  for (int m=1; m<64; m<<=1) mx = fmaxf(mx, __shfl_xor(mx, m, 64));
  float e0 = expf(v0 - mx);
  float e1 = (lane < DD-64) ? expf(v1 - mx) : 0.0f;
  float s = e0 + e1;
  #pragma unroll
  for (int m=1; m<64; m<<=1) s += __shfl_xor(s, m, 64);
  float inv = 1.0f / s;
  depth[(size_t)pos*DD + lane] = e0 * inv;
  if (lane < DD-64) depth[(size_t)pos*DD + 64 + lane] = e1 * inv;
}

// ---------------- scatter: one block per position, run-combined along depth ----------------
__global__ void k_scatter(const float* __restrict__ depth, const float* __restrict__ hf,
                          const int* __restrict__ sidb, float* __restrict__ bev){
  int pos = blockIdx.x;
  int img = pos / NPIX; int p = pos - img*NPIX;
  __shared__ float sdep[DD];
  __shared__ float swt[DD];
  __shared__ int   ssid[DD];
  __shared__ float sctx[COUT];
  int t = threadIdx.x;
  if (t < DD){
    sdep[t] = depth[(size_t)pos*DD + t];
    ssid[t] = sidb[(size_t)(img*DD + t)*NPIX + p];
  }
  if (t < COUT) sctx[t] = hf[(size_t)pos*192 + DD + t];
  __syncthreads();
  if (t < DD){
    int s = ssid[t];
    float w = 0.0f;
    bool head = (s >= 0) && (t == 0 || ssid[t-1] != s);
    if (head){
      for (int dd = t; dd < DD && ssid[dd] == s; ++dd) w += sdep[dd];
    }
    swt[t] = head ? w : 0.0f;     // depth > 0 always, so w>0 marks a head
  }
  __syncthreads();
  for (int j = t; j < DD*COUT; j += blockDim.x){
    int d = j / COUT, c = j - d*COUT;
    float w = swt[d];
    if (w > 0.0f) atomicAdd(&bev[(size_t)ssid[d]*COUT + c], w * sctx[c]);
  }
}

// ---------------- final transpose [b][yx][c] -> [b][c][yx] ----------------
__global__ void k_transpose(const float* __restrict__ bev, float* __restrict__ out){
  int i = blockIdx.x*blockDim.x + threadIdx.x;   // 2621440 exactly
  int yx = i & (YX-1); int rest = i >> 14;
  int c = rest % COUT; int b = rest / COUT;
  out[i] = bev[((size_t)(b*YX + yx))*COUT + c];
}

// ---------------- host ----------------
extern "C" void kernel_launch(void* const* d_in, const int* in_sizes, int n_in,
                              void* d_out, int out_size, void* d_ws, size_t ws_size,
                              hipStream_t stream) {
  const float* feat = (const float*)d_in[0];
  const float* w1   = (const float*)d_in[1];
  const float* g1   = (const float*)d_in[2];
  const float* b1   = (const float*)d_in[3];
  const float* m1   = (const float*)d_in[4];
  const float* v1   = (const float*)d_in[5];
  const float* w2   = (const float*)d_in[6];
  const float* g2   = (const float*)d_in[7];
  const float* b2   = (const float*)d_in[8];
  const float* m2   = (const float*)d_in[9];
  const float* v2   = (const float*)d_in[10];
  const float* wout = (const float*)d_in[11];
  const float* bout = (const float*)d_in[12];
  const float* s2e  = (const float*)d_in[13];
  const float* s2v  = (const float*)d_in[14];
  const float* intr = (const float*)d_in[15];
  const float* ida  = (const float*)d_in[16];
  const float* refh = (const float*)d_in[17];
  const float* bda  = (const float*)d_in[18];

  uint8_t* base = (uint8_t*)d_ws;
  size_t off = 0;
  auto alloc = [&](size_t bytes)->void*{
    void* r = base + off;
    off = (off + bytes + 255) & ~(size_t)255;
    return r;
  };
  unsigned short* wb1   = (unsigned short*)alloc((size_t)CMID*KK*2);
  unsigned short* wb2   = (unsigned short*)alloc((size_t)CMID*KK*2);
  unsigned short* wb3   = (unsigned short*)alloc((size_t)192*CMID*2);
  float* scale1 = (float*)alloc(CMID*4);
  float* bias1  = (float*)alloc(CMID*4);
  float* scale2 = (float*)alloc(CMID*4);
  float* bias2  = (float*)alloc(CMID*4);
  double* mats  = (double*)alloc((size_t)NIMG*MAT_STRIDE*8);
  unsigned short* h1 = (unsigned short*)alloc((size_t)NIMG*CMID*NPIX*2);
  unsigned short* h2 = (unsigned short*)alloc((size_t)NPOS*CMID*2);
  float* hf    = (float*)alloc((size_t)NPOS*192*4);
  float* depth = (float*)alloc((size_t)NPOS*DD*4);
  int*   sid   = (int*)  alloc((size_t)NIMG*DD*NPIX*4);
  float* bev   = (float*)alloc((size_t)NB*YX*COUT*4);

  // im2col buffer: chunk over N-tiles if workspace is tight
  size_t tile_bytes = (size_t)128*KK*2;
  size_t rem = (ws_size > off) ? (ws_size - off) : 0;
  int tiles_fit = (int)(rem / tile_bytes);
  if (tiles_fit < 1) tiles_fit = 1;
  if (tiles_fit > 66) tiles_fit = 66;
  unsigned short* Bt = (unsigned short*)(base + off);

  // prep
  k_f32_to_bf16<<<4608, 256, 0, stream>>>(w1,   wb1, CMID*KK);
  k_f32_to_bf16<<<4608, 256, 0, stream>>>(w2,   wb2, CMID*KK);
  k_f32_to_bf16<<<384,  256, 0, stream>>>(wout, wb3, 192*CMID);
  k_bn_prep<<<2, 256, 0, stream>>>(g1, b1, m1, v1, scale1, bias1);
  k_bn_prep<<<2, 256, 0, stream>>>(g2, b2, m2, v2, scale2, bias2);
  k_prep_mats<<<1, 64, 0, stream>>>(s2e, s2v, intr, ida, refh, bda, mats);
  k_geom<<<3696, 256, 0, stream>>>(mats, sid);

  // conv1: feat -> h1 (NCHW bf16)
  for (int t0 = 0; t0 < 66; t0 += tiles_fit){
    int nt = (66 - t0 < tiles_fit) ? (66 - t0) : tiles_fit;
    int pos0 = t0*128;
    k_im2col<1><<<nt*128, 256, 0, stream>>>(feat, Bt, pos0);
    k_gemm128<0><<<dim3(4, nt), 256, 0, stream>>>(wb1, Bt, KK, scale1, bias1, h1, pos0);
  }
  // conv2: h1 -> h2 ([pos][c] bf16)
  for (int t0 = 0; t0 < 66; t0 += tiles_fit){
    int nt = (66 - t0 < tiles_fit) ? (66 - t0) : tiles_fit;
    int pos0 = t0*128;
    k_im2col<0><<<nt*128, 256, 0, stream>>>(h1, Bt, pos0);
    k_gemm128<1><<<dim3(4, nt), 256, 0, stream>>>(wb2, Bt, KK, scale2, bias2, h2, pos0);
  }
  // conv3 (1x1): h2 -> hf ([pos][192] fp32, +b_out)
  k_gemm64<<<dim3(3, 66), 256, 0, stream>>>(wb3, h2, bout, hf);

  // softmax over depth channels
  k_softmax<<<2112, 256, 0, stream>>>(hf, depth);

  // voxel pooling
  hipMemsetAsync(bev, 0, (size_t)NB*YX*COUT*4, stream);
  k_scatter<<<NPOS, 256, 0, stream>>>(depth, hf, sid, bev);

  // output transpose
  k_transpose<<<10240, 256, 0, stream>>>(bev, (float*)d_out);
}

// Round 2
// 457.777 us; speedup vs baseline: 1.4256x; 1.4256x over previous
//
#include <hip/hip_runtime.h>
#include <stdint.h>

#define NB   2
#define NN   6
#define NIMG 12
#define CIN  512
#define CMID 512
#define DD   112
#define COUT 80
#define FHh  16
#define FWw  44
#define NPIX 704
#define NPOS 8448
#define KK   4608       // 512*9, k = r*512 + ic
#define NXg  128
#define NYg  128
#define YX   16384
#define MAT_STRIDE 56
#define PADPIX 828      // 18*46 padded image
#define PROW 46

typedef short short8 __attribute__((ext_vector_type(8)));
typedef float f32x4  __attribute__((ext_vector_type(4)));

#define GLD16(g, l) __builtin_amdgcn_global_load_lds((const __attribute__((address_space(1))) void*)(g), (__attribute__((address_space(3))) void*)(l), 16, 0, 0)

__device__ __forceinline__ unsigned short f2bf(float f){
  unsigned u = __float_as_uint(f);
  u += 0x7fffu + ((u >> 16) & 1u);    // RNE
  return (unsigned short)(u >> 16);
}

__device__ __forceinline__ f32x4 mfma16(short8 a, short8 b, f32x4 c){
  return __builtin_amdgcn_mfma_f32_16x16x32_bf16(a, b, c, 0, 0, 0);
}

// ---------------- prep kernels ----------------
__global__ void k_f32_to_bf16(const float* __restrict__ src, unsigned short* __restrict__ dst, int n){
  for (int i = blockIdx.x*blockDim.x + threadIdx.x; i < n; i += gridDim.x*blockDim.x)
    dst[i] = f2bf(src[i]);
}

// w [oc][ic][3][3] -> [oc][r*512+ic] bf16
__global__ void k_wreorder(const float* __restrict__ src, unsigned short* __restrict__ dst){
  int i = blockIdx.x*blockDim.x + threadIdx.x;   // 512*4608 exactly
  int oc = i / KK; int j = i - oc*KK;
  int r = j >> 9; int ic = j & 511;
  dst[i] = f2bf(src[(size_t)(oc*512 + ic)*9 + r]);
}

__global__ void k_bn_prep(const float* __restrict__ g, const float* __restrict__ b,
                          const float* __restrict__ m, const float* __restrict__ v,
                          float* __restrict__ scale, float* __restrict__ bias){
  int t = blockIdx.x*blockDim.x + threadIdx.x;
  if (t < CMID){
    float s = g[t] / sqrtf(v[t] + 1e-5f);
    scale[t] = s;
    bias[t]  = b[t] - m[t]*s;
  }
}

// feat fp32 NCHW -> padded channels-last bf16 [img][PADPIX][512]
__global__ void k_featpad(const float* __restrict__ feat, unsigned short* __restrict__ dst){
  int blk = blockIdx.x;                 // img*16 + y, 192 blocks
  int img = blk >> 4, y = blk & 15;
  const float* s = feat + (size_t)img*CIN*NPIX + y*FWw;
  unsigned short* d = dst + (size_t)img*PADPIX*512 + ((y+1)*PROW + 1)*512;
  for (int j = threadIdx.x; j < FWw*512; j += 256){
    int x = j >> 9, ic = j & 511;
    d[x*512 + ic] = f2bf(s[(size_t)ic*NPIX + x]);
  }
}

__device__ void inv4(const double* A, double* out){
  double M[4][8];
  for (int i=0;i<4;i++){ for(int j=0;j<4;j++){ M[i][j]=A[i*4+j]; M[i][4+j]=(i==j)?1.0:0.0; } }
  for (int c=0;c<4;c++){
    int piv=c; double best=fabs(M[c][c]);
    for (int r=c+1;r<4;r++){ double a=fabs(M[r][c]); if(a>best){best=a;piv=r;} }
    if (piv!=c){ for(int j=0;j<8;j++){ double tt=M[c][j]; M[c][j]=M[piv][j]; M[piv][j]=tt; } }
    double inv = 1.0 / M[c][c];
    for (int j=0;j<8;j++) M[c][j]*=inv;
    for (int r=0;r<4;r++){ if(r==c) continue; double f=M[r][c];
      for (int j=0;j<8;j++) M[r][j]-=f*M[c][j]; }
  }
  for (int i=0;i<4;i++) for(int j=0;j<4;j++) out[i*4+j]=M[i][4+j];
}
__device__ void mm4(const double* A, const double* Bm, double* C){
  for (int i=0;i<4;i++) for(int j=0;j<4;j++){
    double s=0.0; for(int k=0;k<4;k++) s+=A[i*4+k]*Bm[k*4+j]; C[i*4+j]=s; }
}

__global__ void k_prep_mats(const float* __restrict__ s2e, const float* __restrict__ s2v,
                            const float* __restrict__ intr, const float* __restrict__ ida,
                            const float* __restrict__ refh, const float* __restrict__ bda,
                            double* __restrict__ mats){
  int t = threadIdx.x;
  if (t >= NIMG) return;
  int b = t / NN;
  double Mida[16], Ms2v[16], Mintr[16], Ms2e[16], Mbda[16];
  for (int i=0;i<16;i++){
    Mida[i] =(double)ida [t*16+i];
    Ms2v[i] =(double)s2v [t*16+i];
    Mintr[i]=(double)intr[t*16+i];
    Ms2e[i] =(double)s2e [t*16+i];
    Mbda[i] =(double)bda [b*16+i];
  }
  double* o = mats + (size_t)t*MAT_STRIDE;
  double tmp[16], tmp2[16];
  inv4(Mida, o);
  inv4(Mintr, tmp);  mm4(Ms2v, tmp, o+16);
  inv4(Ms2v, tmp);   mm4(Ms2e, tmp, tmp2);
  mm4(Mbda, tmp2, o+32);
  o[48] = (double)refh[t];
}

// ---------------- geometry ----------------
__global__ void k_geom(const double* __restrict__ mats, int* __restrict__ sid){
  int g = blockIdx.x*blockDim.x + threadIdx.x;       // 946176 exactly
  int img = g / (DD*NPIX); int rem = g - img*(DD*NPIX);
  int d = rem / NPIX; int p = rem - d*NPIX;
  int h = p / FWw; int w = p - h*FWw;
  const double* M = mats + (size_t)img*MAT_STRIDE;
  float xf = (float)w * (703.0f/43.0f);
  float yf = (float)h * 17.0f;
  float df = 2.0f + (float)d * (56.0f/111.0f);
  double x = (double)xf, y = (double)yf, dep = (double)df;
  double p0 = M[0]*x + M[1]*y + M[2]*dep + M[3];
  double p1 = M[4]*x + M[5]*y + M[6]*dep + M[7];
  double p2 = M[8]*x + M[9]*y + M[10]*dep + M[11];
  double p3 = M[12]*x + M[13]*y + M[14]*dep + M[15];
  double height = M[48] - p2;
  double c0 = p0*10.0, c1 = p1*10.0, c2 = 10.0, c3 = p3;
  const double* C = M + 16;
  double q0 = C[0]*c0 + C[1]*c1 + C[2]*c2 + C[3]*c3;
  double q1 = C[4]*c0 + C[5]*c1 + C[6]*c2 + C[7]*c3;
  double q2 = C[8]*c0 + C[9]*c1 + C[10]*c2 + C[11]*c3;
  double ratio = height / q1;
  double r0 = q0*ratio, r1 = q1*ratio, r2 = q2*ratio, r3 = 1.0;
  const double* F = M + 32;
  double gx = F[0]*r0 + F[1]*r1 + F[2]*r2 + F[3]*r3;
  double gy = F[4]*r0 + F[5]*r1 + F[6]*r2 + F[7]*r3;
  double gz = F[8]*r0 + F[9]*r1 + F[10]*r2 + F[11]*r3;
  float gxf = (float)gx, gyf = (float)gy, gzf = (float)gz;
  const float vcx = (float)(-51.2 + 0.4);
  const float ox = vcx - 0.4f;
  const float oy = ox;
  const float oz = -1.0f - 4.0f;
  float tx = (gxf - ox) / 0.8f;
  float ty = (gyf - oy) / 0.8f;
  float tz = (gzf - oz) / 8.0f;
  int ix = (int)tx, iy = (int)ty, iz = (int)tz;
  bool valid = (tx==tx) && (ty==ty) && (tz==tz) &&
               (ix >= 0) && (ix < NXg) && (iy >= 0) && (iy < NYg) && (iz == 0);
  int b = img / NN;
  sid[g] = valid ? (b*YX + iy*NXg + ix) : -1;
}

// ---------------- conv GEMM: implicit im2col, global_load_lds staging ----------------
// W [512][4608] bf16 (k=r*512+ic), src padded NHWC bf16 [12][828][512]
// D rows = pos, cols = oc. OUT_PADDED=1: write padded NHWC (for conv2 input); else [pos][512].
template<int OUT_PADDED>
__global__ __launch_bounds__(256) void k_conv(const unsigned short* __restrict__ W,
    const unsigned short* __restrict__ src,
    const float* __restrict__ scale, const float* __restrict__ bias,
    unsigned short* __restrict__ out){
  __shared__ __align__(16) short As[128*32];
  __shared__ __align__(16) short Bs[128*32];
  int t = threadIdx.x;
  int lane = t & 63, wv = t >> 6;
  int wm = wv >> 1, wn = wv & 1;
  int q = lane >> 4, ml = lane & 15;
  int m0 = blockIdx.x * 128;
  int n0 = blockIdx.y * 128;

  int lrow = lane >> 2;          // 0..15
  int lcol = (lane & 3) * 8;     // shorts
  const unsigned short* agp[2];
  const unsigned short* bgp[2];
  #pragma unroll
  for (int i=0;i<2;i++){
    int seg = wv*2 + i;
    agp[i] = W + (size_t)(m0 + seg*16 + lrow)*KK + lcol;
    int pos = n0 + seg*16 + lrow;
    int img = pos / NPIX; int p = pos - img*NPIX;
    int y = p / FWw; int x = p - y*FWw;
    bgp[i] = src + (size_t)img*PADPIX*512 + ((y+1)*PROW + (x+1))*512 + lcol;
  }

  f32x4 acc[4][4];
  #pragma unroll
  for (int i=0;i<4;i++)
    #pragma unroll
    for (int j=0;j<4;j++) acc[i][j] = (f32x4)0.0f;

  for (int kb = 0; kb < KK; kb += 32){
    int r = kb >> 9;
    int ic0 = kb & 511;
    int r3 = r / 3;
    int koff = (r3*PROW + (r - r3*3))*512 + ic0 - (PROW+1)*512;  // (dy*46+dx)*512 + ic0
    #pragma unroll
    for (int i=0;i<2;i++){
      int seg = wv*2 + i;
      GLD16(agp[i] + kb,   (char*)As + seg*1024);
      GLD16(bgp[i] + koff, (char*)Bs + seg*1024);
    }
    __syncthreads();
    short8 fa[4], fb[4];
    #pragma unroll
    for (int mi=0;mi<4;mi++) fa[mi] = *(const short8*)(As + (wm*64 + mi*16 + ml)*32 + q*8);
    #pragma unroll
    for (int ni=0;ni<4;ni++) fb[ni] = *(const short8*)(Bs + (wn*64 + ni*16 + ml)*32 + q*8);
    #pragma unroll
    for (int mi=0;mi<4;mi++)
      #pragma unroll
      for (int ni=0;ni<4;ni++)
        acc[mi][ni] = mfma16(fb[ni], fa[mi], acc[mi][ni]);   // rows=pos, cols=oc
    __syncthreads();
  }

  #pragma unroll
  for (int mi=0;mi<4;mi++){
    int oc = m0 + wm*64 + mi*16 + ml;
    float s = scale[oc], bb = bias[oc];
    #pragma unroll
    for (int ni=0;ni<4;ni++){
      f32x4 v = acc[mi][ni];
      #pragma unroll
      for (int rr=0;rr<4;rr++){
        int pos = n0 + wn*64 + ni*16 + q*4 + rr;
        float val = fmaxf(v[rr]*s + bb, 0.0f);
        if (OUT_PADDED){
          int img = pos / NPIX; int p = pos - img*NPIX;
          int y = p / FWw; int x = p - y*FWw;
          out[(size_t)img*PADPIX*512 + ((y+1)*PROW + (x+1))*512 + oc] = f2bf(val);
        } else {
          out[(size_t)pos*CMID + oc] = f2bf(val);
        }
      }
    }
  }
}

// ---------------- 1x1 conv-out GEMM: M=192(BM=64), N=8448, K=512 ----------------
__global__ __launch_bounds__(256) void k_gemm64(const unsigned short* __restrict__ A,
    const unsigned short* __restrict__ Bt, const float* __restrict__ bout,
    float* __restrict__ hf){
  const int K = 512;
  __shared__ __align__(16) short As[64][32];
  __shared__ __align__(16) short Bs[128][32];
  int t = threadIdx.x;
  int m0 = blockIdx.x*64; int n0 = blockIdx.y*128;
  int lane = t & 63; int wv = t >> 6; int q = lane >> 4, ml = lane & 15;
  f32x4 acc[8];
  #pragma unroll
  for (int i=0;i<8;i++) acc[i] = (f32x4)0.0f;
  int ar = t >> 2, ac = (t & 3) * 8;
  int br = t >> 1, bc = (t & 1) * 16;
  const unsigned short* pa = A  + (size_t)(m0 + ar)*K + ac;
  const unsigned short* pb = Bt + (size_t)(n0 + br)*K + bc;
  for (int kb = 0; kb < K; kb += 32){
    uint4 av = *(const uint4*)(pa + kb);
    uint4 b0 = *(const uint4*)(pb + kb);
    uint4 b1 = *(const uint4*)(pb + kb + 8);
    __syncthreads();
    *(uint4*)&As[ar][ac] = av;
    *(uint4*)&Bs[br][bc] = b0; *(uint4*)&Bs[br][bc+8] = b1;
    __syncthreads();
    short8 fa = *(const short8*)&As[wv*16 + ml][q*8];
    #pragma unroll
    for (int ni=0;ni<8;ni++){
      short8 fb = *(const short8*)&Bs[ni*16 + ml][q*8];
      acc[ni] = mfma16(fb, fa, acc[ni]);     // rows = pos, cols = oc
    }
  }
  int oc = m0 + wv*16 + ml;
  float bb = bout[oc];
  #pragma unroll
  for (int ni=0;ni<8;ni++)
    #pragma unroll
    for (int r=0;r<4;r++){
      int pos = n0 + ni*16 + q*4 + r;
      hf[(size_t)pos*192 + oc] = acc[ni][r] + bb;
    }
}

// ---------------- depth softmax ----------------
__global__ void k_softmax(const float* __restrict__ hf, float* __restrict__ depth){
  int pos = blockIdx.x*4 + (threadIdx.x >> 6);
  int lane = threadIdx.x & 63;
  const float* row = hf + (size_t)pos*192;
  float v0 = row[lane];
  float v1 = (lane < DD-64) ? row[64 + lane] : -1e30f;
  float mx = fmaxf(v0, v1);
  #pragma unroll
  for (int m=1; m<64; m<<=1) mx = fmaxf(mx, __shfl_xor(mx, m, 64));
  float e0 = expf(v0 - mx);
  float e1 = (lane < DD-64) ? expf(v1 - mx) : 0.0f;
  float s = e0 + e1;
  #pragma unroll
  for (int m=1; m<64; m<<=1) s += __shfl_xor(s, m, 64);
  float inv = 1.0f / s;
  depth[(size_t)pos*DD + lane] = e0 * inv;
  if (lane < DD-64) depth[(size_t)pos*DD + 64 + lane] = e1 * inv;
}

// ---------------- scatter ----------------
__global__ void k_scatter(const float* __restrict__ depth, const float* __restrict__ hf,
                          const int* __restrict__ sidb, float* __restrict__ bev){
  int pos = blockIdx.x;
  int img = pos / NPIX; int p = pos - img*NPIX;
  __shared__ float sdep[DD];
  __shared__ float swt[DD];
  __shared__ int   ssid[DD];
  __shared__ float sctx[COUT];
  int t = threadIdx.x;
  if (t < DD){
    sdep[t] = depth[(size_t)pos*DD + t];
    ssid[t] = sidb[(size_t)(img*DD + t)*NPIX + p];
  }
  if (t < COUT) sctx[t] = hf[(size_t)pos*192 + DD + t];
  __syncthreads();
  if (t < DD){
    int s = ssid[t];
    float w = 0.0f;
    bool head = (s >= 0) && (t == 0 || ssid[t-1] != s);
    if (head){
      for (int dd = t; dd < DD && ssid[dd] == s; ++dd) w += sdep[dd];
    }
    swt[t] = head ? w : 0.0f;
  }
  __syncthreads();
  for (int j = t; j < DD*COUT; j += blockDim.x){
    int d = j / COUT, c = j - d*COUT;
    float w = swt[d];
    if (w > 0.0f) atomicAdd(&bev[(size_t)ssid[d]*COUT + c], w * sctx[c]);
  }
}

// ---------------- final transpose ----------------
__global__ void k_transpose(const float* __restrict__ bev, float* __restrict__ out){
  int i = blockIdx.x*blockDim.x + threadIdx.x;   // 2621440 exactly
  int yx = i & (YX-1); int rest = i >> 14;
  int c = rest % COUT; int b = rest / COUT;
  out[i] = bev[((size_t)(b*YX + yx))*COUT + c];
}

// ---------------- host ----------------
extern "C" void kernel_launch(void* const* d_in, const int* in_sizes, int n_in,
                              void* d_out, int out_size, void* d_ws, size_t ws_size,
                              hipStream_t stream) {
  const float* feat = (const float*)d_in[0];
  const float* w1   = (const float*)d_in[1];
  const float* g1   = (const float*)d_in[2];
  const float* b1   = (const float*)d_in[3];
  const float* m1   = (const float*)d_in[4];
  const float* v1   = (const float*)d_in[5];
  const float* w2   = (const float*)d_in[6];
  const float* g2   = (const float*)d_in[7];
  const float* b2   = (const float*)d_in[8];
  const float* m2   = (const float*)d_in[9];
  const float* v2   = (const float*)d_in[10];
  const float* wout = (const float*)d_in[11];
  const float* bout = (const float*)d_in[12];
  const float* s2e  = (const float*)d_in[13];
  const float* s2v  = (const float*)d_in[14];
  const float* intr = (const float*)d_in[15];
  const float* ida  = (const float*)d_in[16];
  const float* refh = (const float*)d_in[17];
  const float* bda  = (const float*)d_in[18];

  uint8_t* base = (uint8_t*)d_ws;
  size_t off = 0;
  auto alloc = [&](size_t bytes)->void*{
    void* r = base + off;
    off = (off + bytes + 255) & ~(size_t)255;
    return r;
  };
  unsigned short* wb1 = (unsigned short*)alloc((size_t)CMID*KK*2);
  unsigned short* wb2 = (unsigned short*)alloc((size_t)CMID*KK*2);
  unsigned short* wb3 = (unsigned short*)alloc((size_t)192*CMID*2);
  float* scale1 = (float*)alloc(CMID*4);
  float* bias1  = (float*)alloc(CMID*4);
  float* scale2 = (float*)alloc(CMID*4);
  float* bias2  = (float*)alloc(CMID*4);
  double* mats  = (double*)alloc((size_t)NIMG*MAT_STRIDE*8);

  size_t padded_bytes = (size_t)NIMG*PADPIX*512*2;          // 10.2 MB
  // region E: featpad, later h2 ([pos][512] bf16 = 8.7 MB)
  uint8_t* regionE = (uint8_t*)alloc(padded_bytes);
  // region F: h1pad, later hf ([pos][192] fp32 = 6.5 MB)
  uint8_t* regionF = (uint8_t*)alloc(padded_bytes);
  float* depth = (float*)alloc((size_t)NPOS*DD*4);
  int*   sid   = (int*)  alloc((size_t)NIMG*DD*NPIX*4);
  float* bev   = (float*)alloc((size_t)NB*YX*COUT*4);

  unsigned short* featpad = (unsigned short*)regionE;
  unsigned short* h2      = (unsigned short*)regionE;
  unsigned short* h1pad   = (unsigned short*)regionF;
  float*          hf      = (float*)regionF;

  // prep
  k_wreorder<<<9216, 256, 0, stream>>>(w1, wb1);
  k_wreorder<<<9216, 256, 0, stream>>>(w2, wb2);
  k_f32_to_bf16<<<384, 256, 0, stream>>>(wout, wb3, 192*CMID);
  k_bn_prep<<<2, 256, 0, stream>>>(g1, b1, m1, v1, scale1, bias1);
  k_bn_prep<<<2, 256, 0, stream>>>(g2, b2, m2, v2, scale2, bias2);
  k_prep_mats<<<1, 64, 0, stream>>>(s2e, s2v, intr, ida, refh, bda, mats);
  k_geom<<<3696, 256, 0, stream>>>(mats, sid);

  hipMemsetAsync(featpad, 0, padded_bytes, stream);
  hipMemsetAsync(h1pad,   0, padded_bytes, stream);
  k_featpad<<<192, 256, 0, stream>>>(feat, featpad);

  // conv1: featpad -> h1pad (padded NHWC bf16)
  k_conv<1><<<dim3(4, 66), 256, 0, stream>>>(wb1, featpad, scale1, bias1, h1pad);
  // conv2: h1pad -> h2 ([pos][512] bf16)
  k_conv<0><<<dim3(4, 66), 256, 0, stream>>>(wb2, h1pad, scale2, bias2, h2);
  // conv3 (1x1): h2 -> hf ([pos][192] fp32, +b_out)
  k_gemm64<<<dim3(3, 66), 256, 0, stream>>>(wb3, h2, bout, hf);

  k_softmax<<<2112, 256, 0, stream>>>(hf, depth);

  hipMemsetAsync(bev, 0, (size_t)NB*YX*COUT*4, stream);
  k_scatter<<<NPOS, 256, 0, stream>>>(depth, hf, sid, bev);

  k_transpose<<<10240, 256, 0, stream>>>(bev, (float*)d_out);
}